// Round 11
// baseline (70.499 us; speedup 1.0000x reference)
//
#include <hip/hip_runtime.h>
#include <stdint.h>

// VectorQuantizer: x[32,64,64,64] NCHW fp32, W[512,64] fp32.
// argmin_k ||x - w_k||^2 ; out = W[argmin] in NCHW.
//
// v11 = v10 with 2x A-fragment amortization: 512-thr blocks, 8 waves x 32
// tokens/wave (two B-fragment sets share each A-read -> half the LDS bytes
// per score). Full codebook in LDS dim-octet-major (0 conflicts), direct
// global B-frags, 2-pass margin-certified argmax (2^-7*||x||*Wmax+0.02),
// fp64 refine, coalesced direct I/O. launch_bounds(512,4): 128-reg cap.

typedef short short8 __attribute__((ext_vector_type(8)));
typedef float f32x4 __attribute__((ext_vector_type(4)));

#define HW_ 4096

__device__ __forceinline__ unsigned short f2bf(float f) {
    unsigned u = __float_as_uint(f);
    u += 0x7fff + ((u >> 16) & 1);   // RNE to bf16
    return (unsigned short)(u >> 16);
}

// Image: ushort idx(k,d) = (d>>3)*4096 + k*8 + (d&7)   [8 octet-planes of 8KiB]
__global__ __launch_bounds__(64) void vq_prep(const float* __restrict__ W,
                                              unsigned short* __restrict__ Wb,
                                              float* __restrict__ nh,
                                              int* __restrict__ wmax2i) {
    const int k = blockIdx.x, l = threadIdx.x;
    float v = W[k * 64 + l];
    Wb[(l >> 3) * 4096 + k * 8 + (l & 7)] = f2bf(v);
    float s = v * v;
    #pragma unroll
    for (int off = 1; off < 64; off <<= 1) s += __shfl_xor(s, off);
    if (l == 0) {
        nh[k] = -0.5f * s;
        atomicMax(wmax2i, __float_as_int(s));   // s > 0: int order == float order
    }
}

__global__ __launch_bounds__(512, 4) void vq_main(const float* __restrict__ x,
                                                  const float* __restrict__ W,
                                                  const unsigned short* __restrict__ Wb,
                                                  const float* __restrict__ nh,
                                                  const int* __restrict__ wmax2i,
                                                  float* __restrict__ out) {
    __shared__ unsigned short cb[32768];   // 64 KiB codebook, dim-octet-major
    __shared__ float nhs[512];             // -0.5*||w||^2 (f32)
    __shared__ int bkArr[256];

    const int tid = threadIdx.x;
    const int bid = blockIdx.x;
    const int b = bid >> 4;                 // batch 0..31
    const int p0 = (bid & 15) << 8;         // 256-token spatial base
    const int l = tid & 63;
    const int wv = tid >> 6;                // wave 0..7
    const int g = l >> 4;                   // k-dim octet group 0..3
    const int tokw = l & 15;
    const int tokA = wv * 32 + tokw;        // block token set A
    const int tokB = tokA + 16;             // block token set B

    // ---- stage codebook + nhs (linear, conflict-free) ----
    {
        const f32x4* src = (const f32x4*)Wb;
        f32x4* dst = (f32x4*)cb;
        #pragma unroll
        for (int i = 0; i < 8; ++i) dst[tid + i * 512] = src[tid + i * 512];
        nhs[tid] = nh[tid];
    }

    // ---- B fragments direct from global; xsq on the fly ----
    short8 bfA0, bfA1, bfB0, bfB1;
    float xsqA = 0.f, xsqB = 0.f;
    {
        const float* xa = x + (size_t)b * 262144 + p0 + tokA;
        const float* xbp = x + (size_t)b * 262144 + p0 + tokB;
        #pragma unroll
        for (int e = 0; e < 8; ++e) {
            float va = xa[(size_t)(g * 8 + e) * HW_];
            float vb = xbp[(size_t)(g * 8 + e) * HW_];
            xsqA += va * va; xsqB += vb * vb;
            bfA0[e] = (short)f2bf(va);
            bfB0[e] = (short)f2bf(vb);
        }
        #pragma unroll
        for (int e = 0; e < 8; ++e) {
            float va = xa[(size_t)(32 + g * 8 + e) * HW_];
            float vb = xbp[(size_t)(32 + g * 8 + e) * HW_];
            xsqA += va * va; xsqB += vb * vb;
            bfA1[e] = (short)f2bf(va);
            bfB1[e] = (short)f2bf(vb);
        }
    }
    xsqA += __shfl_xor(xsqA, 16); xsqA += __shfl_xor(xsqA, 32);
    xsqB += __shfl_xor(xsqB, 16); xsqB += __shfl_xor(xsqB, 32);
    const float wm2 = __int_as_float(*wmax2i);
    const float marginA = ldexpf(sqrtf(xsqA * wm2), -7) + 0.02f;  // 2E certified
    const float marginB = ldexpf(sqrtf(xsqB * wm2), -7) + 0.02f;
    __syncthreads();

    // A-read for tile t: code = t*16 + tokw, octet-planes g and g+4
    const char* Ab = (const char*)cb + g * 8192 + tokw * 16;

    // ---- pass 1: running maxes (both token sets share each A-read) ----
    float mA = -3.4e38f, mB = -3.4e38f;
    #pragma unroll 1
    for (int tc = 0; tc < 4; ++tc) {
        #pragma unroll
        for (int tt = 0; tt < 8; ++tt) {
            const int t = tc * 8 + tt;
            short8 a0 = *(const short8*)(Ab + t * 256);
            short8 a1 = *(const short8*)(Ab + 32768 + t * 256);
            f32x4 nhv = *(const f32x4*)(&nhs[t * 16 + g * 4]);
            f32x4 accA = nhv;
            accA = __builtin_amdgcn_mfma_f32_16x16x32_bf16(a0, bfA0, accA, 0, 0, 0);
            accA = __builtin_amdgcn_mfma_f32_16x16x32_bf16(a1, bfA1, accA, 0, 0, 0);
            f32x4 accB = nhv;
            accB = __builtin_amdgcn_mfma_f32_16x16x32_bf16(a0, bfB0, accB, 0, 0, 0);
            accB = __builtin_amdgcn_mfma_f32_16x16x32_bf16(a1, bfB1, accB, 0, 0, 0);
            mA = fmaxf(mA, fmaxf(fmaxf(accA[0], accA[1]), fmaxf(accA[2], accA[3])));
            mB = fmaxf(mB, fmaxf(fmaxf(accB[0], accB[1]), fmaxf(accB[2], accB[3])));
        }
    }
    mA = fmaxf(mA, __shfl_xor(mA, 16)); mA = fmaxf(mA, __shfl_xor(mA, 32));
    mB = fmaxf(mB, __shfl_xor(mB, 16)); mB = fmaxf(mB, __shfl_xor(mB, 32));
    const float thrA = mA - marginA;
    const float thrB = mB - marginB;

    // ---- pass 2: rescan, candidate masks (slot = t*4 + r, k = t*16+g*4+r) ----
    uint64_t c0mA = 0, c1mA = 0, c0mB = 0, c1mB = 0;
    #pragma unroll 1
    for (int tc = 0; tc < 4; ++tc) {
        uint64_t loA = 0, loB = 0;
        #pragma unroll
        for (int tt = 0; tt < 8; ++tt) {
            const int t = tc * 8 + tt;
            short8 a0 = *(const short8*)(Ab + t * 256);
            short8 a1 = *(const short8*)(Ab + 32768 + t * 256);
            f32x4 nhv = *(const f32x4*)(&nhs[t * 16 + g * 4]);
            f32x4 accA = nhv;
            accA = __builtin_amdgcn_mfma_f32_16x16x32_bf16(a0, bfA0, accA, 0, 0, 0);
            accA = __builtin_amdgcn_mfma_f32_16x16x32_bf16(a1, bfA1, accA, 0, 0, 0);
            f32x4 accB = nhv;
            accB = __builtin_amdgcn_mfma_f32_16x16x32_bf16(a0, bfB0, accB, 0, 0, 0);
            accB = __builtin_amdgcn_mfma_f32_16x16x32_bf16(a1, bfB1, accB, 0, 0, 0);
            unsigned bitsA = 0, bitsB = 0;
            #pragma unroll
            for (int r = 0; r < 4; ++r) {
                bitsA |= (accA[r] >= thrA ? 1u : 0u) << r;
                bitsB |= (accB[r] >= thrB ? 1u : 0u) << r;
            }
            loA |= (uint64_t)bitsA << (tt * 4);
            loB |= (uint64_t)bitsB << (tt * 4);
        }
        if (tc == 0) { c0mA |= loA; c0mB |= loB; }
        else if (tc == 1) { c0mA |= loA << 32; c0mB |= loB << 32; }
        else if (tc == 2) { c1mA |= loA; c1mB |= loB; }
        else { c1mA |= loA << 32; c1mB |= loB << 32; }
    }

    // ================= set A resolution =================
    int bkA;
    {
        const int cnt = __popcll(c0mA) + __popcll(c1mA);
        int cnt4 = cnt;
        cnt4 += __shfl_xor(cnt4, 16);
        cnt4 += __shfl_xor(cnt4, 32);
        int klocal = 0x7fffffff;
        if (cnt == 1) {
            int slot = c0mA ? __builtin_ctzll(c0mA) : 64 + __builtin_ctzll(c1mA);
            klocal = (slot >> 2) * 16 + g * 4 + (slot & 3);
        }
        int kmin = klocal;
        kmin = min(kmin, __shfl_xor(kmin, 16));
        kmin = min(kmin, __shfl_xor(kmin, 32));

        double bd = 1.0e308;
        int bkm = 0x7fffffff;
        const bool multi = (cnt4 > 1);
        if (!multi) { c0mA = 0; c1mA = 0; }
        uint64_t wmask = __ballot((c0mA | c1mA) != 0ull);
        while (wmask) {
            int L = __builtin_ctzll(wmask);
            wmask &= wmask - 1;
            uint64_t mm0 = __shfl(c0mA, L);
            uint64_t mm1 = __shfl(c1mA, L);
            const int gL = L >> 4;
            const int tokL = wv * 32 + (L & 15);
            double xvd = (double)x[(size_t)(b * 64 + l) * HW_ + p0 + tokL];
            while (mm0 | mm1) {
                int k;
                if (mm0) {
                    int s2 = __builtin_ctzll(mm0); mm0 &= mm0 - 1;
                    k = (s2 >> 2) * 16 + gL * 4 + (s2 & 3);
                } else {
                    int s2 = __builtin_ctzll(mm1); mm1 &= mm1 - 1;
                    k = ((s2 >> 2) + 16) * 16 + gL * 4 + (s2 & 3);
                }
                double dl = xvd - (double)W[k * 64 + l];
                double p = dl * dl;
                #pragma unroll
                for (int off = 1; off < 64; off <<= 1) p += __shfl_xor(p, off);
                if (l == L && (p < bd || (p == bd && k < bkm))) { bd = p; bkm = k; }
            }
        }
        double od = __shfl_xor(bd, 16); int ok = __shfl_xor(bkm, 16);
        if (od < bd || (od == bd && ok < bkm)) { bd = od; bkm = ok; }
        od = __shfl_xor(bd, 32); ok = __shfl_xor(bkm, 32);
        if (od < bd || (od == bd && ok < bkm)) { bd = od; bkm = ok; }
        bkA = multi ? bkm : kmin;
    }

    // ================= set B resolution =================
    int bkB;
    {
        const int cnt = __popcll(c0mB) + __popcll(c1mB);
        int cnt4 = cnt;
        cnt4 += __shfl_xor(cnt4, 16);
        cnt4 += __shfl_xor(cnt4, 32);
        int klocal = 0x7fffffff;
        if (cnt == 1) {
            int slot = c0mB ? __builtin_ctzll(c0mB) : 64 + __builtin_ctzll(c1mB);
            klocal = (slot >> 2) * 16 + g * 4 + (slot & 3);
        }
        int kmin = klocal;
        kmin = min(kmin, __shfl_xor(kmin, 16));
        kmin = min(kmin, __shfl_xor(kmin, 32));

        double bd = 1.0e308;
        int bkm = 0x7fffffff;
        const bool multi = (cnt4 > 1);
        if (!multi) { c0mB = 0; c1mB = 0; }
        uint64_t wmask = __ballot((c0mB | c1mB) != 0ull);
        while (wmask) {
            int L = __builtin_ctzll(wmask);
            wmask &= wmask - 1;
            uint64_t mm0 = __shfl(c0mB, L);
            uint64_t mm1 = __shfl(c1mB, L);
            const int gL = L >> 4;
            const int tokL = wv * 32 + 16 + (L & 15);
            double xvd = (double)x[(size_t)(b * 64 + l) * HW_ + p0 + tokL];
            while (mm0 | mm1) {
                int k;
                if (mm0) {
                    int s2 = __builtin_ctzll(mm0); mm0 &= mm0 - 1;
                    k = (s2 >> 2) * 16 + gL * 4 + (s2 & 3);
                } else {
                    int s2 = __builtin_ctzll(mm1); mm1 &= mm1 - 1;
                    k = ((s2 >> 2) + 16) * 16 + gL * 4 + (s2 & 3);
                }
                double dl = xvd - (double)W[k * 64 + l];
                double p = dl * dl;
                #pragma unroll
                for (int off = 1; off < 64; off <<= 1) p += __shfl_xor(p, off);
                if (l == L && (p < bd || (p == bd && k < bkm))) { bd = p; bkm = k; }
            }
        }
        double od = __shfl_xor(bd, 16); int ok = __shfl_xor(bkm, 16);
        if (od < bd || (od == bd && ok < bkm)) { bd = od; bkm = ok; }
        od = __shfl_xor(bd, 32); ok = __shfl_xor(bkm, 32);
        if (od < bd || (od == bd && ok < bkm)) { bd = od; bkm = ok; }
        bkB = multi ? bkm : kmin;
    }

    if (g == 0) { bkArr[tokA] = bkA; bkArr[tokB] = bkB; }
    __syncthreads();

    // ---- epilogue: gather W rows (L2-hot), coalesced NCHW store ----
    {
        const int pp = tid & 255;            // token
        const int dh = tid >> 8;             // dim half 0..1
        const int kk = bkArr[pp];
        const float* wr = W + kk * 64 + dh * 32;
        float* ob = out + (size_t)b * 262144 + p0 + pp;
        #pragma unroll
        for (int j = 0; j < 8; ++j) {
            f32x4 v = *(const f32x4*)(wr + j * 4);
            ob[(size_t)(dh * 32 + j * 4 + 0) * HW_] = v[0];
            ob[(size_t)(dh * 32 + j * 4 + 1) * HW_] = v[1];
            ob[(size_t)(dh * 32 + j * 4 + 2) * HW_] = v[2];
            ob[(size_t)(dh * 32 + j * 4 + 3) * HW_] = v[3];
        }
    }
}

extern "C" void kernel_launch(void* const* d_in, const int* in_sizes, int n_in,
                              void* d_out, int out_size, void* d_ws, size_t ws_size,
                              hipStream_t stream) {
    const float* x = (const float*)d_in[0];
    const float* W = (const float*)d_in[1];
    unsigned short* Wb = (unsigned short*)d_ws;              // 64 KiB image
    float* nh = (float*)((char*)d_ws + 65536);               // 512 f32
    int* wmax2i = (int*)((char*)d_ws + 65536 + 2048);        // 1 int (float bits)
    hipMemsetAsync(wmax2i, 0, 4, stream);
    vq_prep<<<512, 64, 0, stream>>>(W, Wb, nh, wmax2i);
    vq_main<<<512, 512, 0, stream>>>(x, W, Wb, nh, wmax2i, (float*)d_out);
}